// Round 5
// baseline (110.409 us; speedup 1.0000x reference)
//
#include <hip/hip_runtime.h>

// Problem constants
#define BATCH 16384
#define KEYD  64
#define DDIM  128
#define UDIM  128
#define MODES 32

typedef __attribute__((ext_vector_type(8))) short bf16x8;   // 8 bf16 in 4 VGPRs
typedef __attribute__((ext_vector_type(4))) float f32x4;

__device__ __forceinline__ unsigned short f2bf(float f) {
  unsigned u = __float_as_uint(f);
  unsigned r = (u + 0x7FFFu + ((u >> 16) & 1u)) >> 16;  // RNE bf16
  return (unsigned short)r;
}

__device__ __forceinline__ void gld_lds16(const void* g, void* l) {
  __builtin_amdgcn_global_load_lds(
      (const __attribute__((address_space(1))) unsigned int*)g,
      (__attribute__((address_space(3))) unsigned int*)l, 16, 0, 0);
}

// ---------------------------------------------------------------------------
// Fused prep (one dispatch) — unchanged from R4 (measured fast):
//  blocks [0,512): sim softmax (32 rows/block) + x->bf16 cast.
//  blocks [512,770): cast kernels+biases to bf16 in MFMA-B fragment layout
//    kb16[m][kblk][u][j] = kernels[m][kblk*8+j][u].
// ---------------------------------------------------------------------------
__global__ __launch_bounds__(256) void prep_all(
    const float* __restrict__ key, const float* __restrict__ x,
    const float* __restrict__ sens, const float* __restrict__ keys_map,
    const float* __restrict__ kernels, const float* __restrict__ biases,
    float* __restrict__ sim, unsigned short* __restrict__ x16,
    unsigned short* __restrict__ kb16, unsigned short* __restrict__ bb16) {
  const int t = threadIdx.x;
  const int bid = blockIdx.x;

  if (bid < BATCH / 32) {
    __shared__ float kr[32][KEYD];  // 32 key rows, 8KB
    *(float4*)(&kr[0][0] + t * 4) =
        *(const float4*)(key + (long)bid * 32 * KEYD + t * 4);
    *(float4*)(&kr[0][0] + 1024 + t * 4) =
        *(const float4*)(key + (long)bid * 32 * KEYD + 1024 + t * 4);

    const int lane = t & 63, wave = t >> 6;
    const int m = lane & 31, h = lane >> 5;
    float kreg[32];  // this lane's half of mode m's key row
    {
      const float* kmp = keys_map + m * KEYD + h * 32;
      #pragma unroll
      for (int j = 0; j < 32; j += 4) {
        const float4 v = *(const float4*)(kmp + j);
        kreg[j] = v.x; kreg[j + 1] = v.y; kreg[j + 2] = v.z; kreg[j + 3] = v.w;
      }
    }
    const float sv = sens[m];
    __syncthreads();

    #pragma unroll
    for (int rr = 0; rr < 8; ++rr) {
      const int rl = wave * 8 + rr;
      const long row = (long)bid * 32 + rl;

      float d2h = 0.f;
      #pragma unroll
      for (int j = 0; j < 32; j += 2) {
        const float2 kv = *(const float2*)(&kr[rl][h * 32 + j]);
        float a = kv.x - kreg[j], b = kv.y - kreg[j + 1];
        d2h += a * a + b * b;
      }
      float d2 = d2h + __shfl_xor(d2h, 32, 64);
      float logit = sv / (sqrtf(d2) + 1.0f);
      float mx = logit;
      #pragma unroll
      for (int off = 16; off > 0; off >>= 1) mx = fmaxf(mx, __shfl_xor(mx, off, 64));
      float e = __expf(logit - mx);
      float s = e;
      #pragma unroll
      for (int off = 16; off > 0; off >>= 1) s += __shfl_xor(s, off, 64);
      if (h == 0) sim[row * MODES + m] = e / s;

      const float2 xv = *(const float2*)(x + row * DDIM + lane * 2);
      ushort2 o; o.x = f2bf(xv.x); o.y = f2bf(xv.y);
      *(ushort2*)(x16 + row * DDIM + lane * 2) = o;
    }
  } else {
    int tt = (bid - BATCH / 32) * 256 + t;
    if (tt < MODES * 16 * UDIM) {  // 65536 chunks of 8
      int u = tt & 127, kb = (tt >> 7) & 15, m = tt >> 11;
      const float* src = kernels + (long)((m * 16 + kb) * 8) * UDIM + u;
      ushort4 lo, hi;
      lo.x = f2bf(src[0 * UDIM]); lo.y = f2bf(src[1 * UDIM]);
      lo.z = f2bf(src[2 * UDIM]); lo.w = f2bf(src[3 * UDIM]);
      hi.x = f2bf(src[4 * UDIM]); hi.y = f2bf(src[5 * UDIM]);
      hi.z = f2bf(src[6 * UDIM]); hi.w = f2bf(src[7 * UDIM]);
      *(ushort4*)(kb16 + (long)tt * 8) = lo;
      *(ushort4*)(kb16 + (long)tt * 8 + 4) = hi;
    } else {  // 512 bias chunks
      int tb = tt - MODES * 16 * UDIM;
      int u = tb & 127, kb = tb >> 7;
      const float* src = biases + kb * 8 * UDIM + u;
      ushort4 lo, hi;
      lo.x = f2bf(src[0 * UDIM]); lo.y = f2bf(src[1 * UDIM]);
      lo.z = f2bf(src[2 * UDIM]); lo.w = f2bf(src[3 * UDIM]);
      hi.x = f2bf(src[4 * UDIM]); hi.y = f2bf(src[5 * UDIM]);
      hi.z = f2bf(src[6 * UDIM]); hi.w = f2bf(src[7 * UDIM]);
      *(ushort4*)(bb16 + (long)tb * 8) = lo;
      *(ushort4*)(bb16 + (long)tb * 8 + 4) = hi;
    }
  }
}

// ---------------------------------------------------------------------------
// GEMM.  Block tile 128 rows x 64 cols; 4 waves stacked in rows (wave 32x64).
// Grid (128 rowtiles, 2 colhalves x 4 modesplits) = 1024 blocks, ~3/CU
// resident (20KB LDS, launch_bounds(256,3)) -> cross-block overlap hides the
// per-mode barrier drain (m97-style single-buffer, 2 barriers/mode).
// Plain-store epilogue into per-split partial buffers; reduce kernel sums.
// ---------------------------------------------------------------------------
__global__ __launch_bounds__(256, 3) void gemm_poly(
    const unsigned short* __restrict__ x16, const unsigned short* __restrict__ kb16,
    const unsigned short* __restrict__ bb16, const float* __restrict__ sim,
    float* __restrict__ partial) {
  __shared__ alignas(16) unsigned short bsh[16 * 64 * 8];  // 16KB: [kblk16][u'64][j8]
  __shared__ alignas(16) float simT[8][128];               // [mode_local][row] 4KB

  const int t = threadIdx.x;
  const int lane = t & 63, w = t >> 6;
  const int q = lane >> 4, l16 = lane & 15;
  const int wrow = w * 32;                  // wave's rows in block tile
  const long bm = (long)blockIdx.x * 128;
  const int split = blockIdx.y & 3;         // modes [split*8, split*8+8)
  const int c0 = (blockIdx.y >> 2) * 64;    // column half

  {  // stage sim (own 8 modes, 128 rows) transposed into LDS
    int rrow = t >> 1, mg = (t & 1) * 4;
    const float4 v = *(const float4*)(sim + (bm + rrow) * MODES + split * 8 + mg);
    simT[mg + 0][rrow] = v.x; simT[mg + 1][rrow] = v.y;
    simT[mg + 2][rrow] = v.z; simT[mg + 3][rrow] = v.w;
  }

  // A fragments (x, bf16): A[row = wrow+rt*16+l16][k = ks*32+q*8+j]
  bf16x8 aF[2][4];
  #pragma unroll
  for (int rt = 0; rt < 2; ++rt)
    #pragma unroll
    for (int ks = 0; ks < 4; ++ks)
      aF[rt][ks] = *(const bf16x8*)(x16 + (bm + wrow + rt * 16 + l16) * DDIM + ks * 32 + q * 8);

  f32x4 acc[2][4] = {};  // [rt][ct]

  for (int mi = 0; mi < 8; ++mi) {
    const int m = split * 8 + mi;
    __syncthreads();  // prev-iter bsh reads done (and simT staged, iter 0)
    {  // stage this mode's 64-column slice: 16 chunks of 1KB, flat in LDS
      const unsigned short* msrc = kb16 + (long)m * (16 * UDIM * 8) + c0 * 8;
      #pragma unroll
      for (int i = 0; i < 4; ++i) {
        int e = (t + i * 256) * 8;              // LDS elem offset (16B/lane)
        int kblk = e >> 9, within = e & 511;    // 512 elems per kblk chunk
        gld_lds16(msrc + (long)kblk * (UDIM * 8) + within,
                  (unsigned short*)bsh + e);
      }
    }
    __syncthreads();  // vmcnt(0) drain: tile staged

    bf16x8 bF[4][4];  // [ks][ct]: contiguous 16B, 2-way-free bank pattern
    #pragma unroll
    for (int ks = 0; ks < 4; ++ks)
      #pragma unroll
      for (int ct = 0; ct < 4; ++ct)
        bF[ks][ct] = *(const bf16x8*)&bsh[(((ks * 4 + q) * 64) + ct * 16 + l16) * 8];

    #pragma unroll
    for (int rt = 0; rt < 2; ++rt) {
      f32x4 tmp[4] = {};
      #pragma unroll
      for (int ks = 0; ks < 4; ++ks)
        #pragma unroll
        for (int ct = 0; ct < 4; ++ct)
          tmp[ct] = __builtin_amdgcn_mfma_f32_16x16x32_bf16(aF[rt][ks], bF[ks][ct], tmp[ct], 0, 0, 0);
      const f32x4 s = *(const f32x4*)&simT[mi][wrow + rt * 16 + q * 4];
      #pragma unroll
      for (int ct = 0; ct < 4; ++ct)
        acc[rt][ct] += s * tmp[ct];
    }
  }

  // bias term: one K=32 MFMA round (A = sim bf16, B = biases). split 0 only.
  if (split == 0) {
    bf16x8 sF[2];
    #pragma unroll
    for (int rt = 0; rt < 2; ++rt) {
      const float* sp = sim + (bm + wrow + rt * 16 + l16) * MODES + q * 8;
      bf16x8 f;
      #pragma unroll
      for (int j = 0; j < 8; ++j) f[j] = (short)f2bf(sp[j]);
      sF[rt] = f;
    }
    #pragma unroll
    for (int ct = 0; ct < 4; ++ct) {
      bf16x8 bb = *(const bf16x8*)(bb16 + (long)(q * UDIM + c0 + ct * 16 + l16) * 8);
      #pragma unroll
      for (int rt = 0; rt < 2; ++rt)
        acc[rt][ct] = __builtin_amdgcn_mfma_f32_16x16x32_bf16(sF[rt], bb, acc[rt][ct], 0, 0, 0);
    }
  }

  // epilogue: plain stores to this split's private partial buffer
  float* part = partial + (long)split * ((long)BATCH * UDIM);
  #pragma unroll
  for (int rt = 0; rt < 2; ++rt)
    #pragma unroll
    for (int ct = 0; ct < 4; ++ct) {
      long row = bm + wrow + rt * 16 + q * 4;
      int col = c0 + ct * 16 + l16;
      #pragma unroll
      for (int r = 0; r < 4; ++r)
        part[(row + r) * UDIM + col] = acc[rt][ct][r];
    }
}

// ---------------------------------------------------------------------------
// Streaming reduce: out = (p0+p1+p2+p3) / MODES.  2M floats as float4.
// ---------------------------------------------------------------------------
__global__ __launch_bounds__(256) void reduce_parts(
    const float* __restrict__ partial, float* __restrict__ out) {
  const long i = ((long)blockIdx.x * 256 + threadIdx.x) * 4;
  const long S = (long)BATCH * UDIM;
  const f32x4 p0 = *(const f32x4*)(partial + i);
  const f32x4 p1 = *(const f32x4*)(partial + S + i);
  const f32x4 p2 = *(const f32x4*)(partial + 2 * S + i);
  const f32x4 p3 = *(const f32x4*)(partial + 3 * S + i);
  *(f32x4*)(out + i) = (p0 + p1 + p2 + p3) * (1.0f / MODES);
}

extern "C" void kernel_launch(void* const* d_in, const int* in_sizes, int n_in,
                              void* d_out, int out_size, void* d_ws, size_t ws_size,
                              hipStream_t stream) {
  const float* key      = (const float*)d_in[0];
  const float* x        = (const float*)d_in[1];
  const float* sens     = (const float*)d_in[2];
  const float* keys_map = (const float*)d_in[3];
  const float* kernels  = (const float*)d_in[4];
  const float* biases   = (const float*)d_in[5];
  float* out = (float*)d_out;

  char* ws = (char*)d_ws;
  float*          sim  = (float*)ws;                          // 2 MB
  unsigned short* x16  = (unsigned short*)(ws + (2u << 20));  // 4 MB
  unsigned short* kb16 = (unsigned short*)(ws + (6u << 20));  // 1 MB
  unsigned short* bb16 = (unsigned short*)(ws + (7u << 20));  // 8 KB
  float*          part = (float*)(ws + (8u << 20));           // 4 x 8.4 MB

  prep_all<<<BATCH / 32 + 258, 256, 0, stream>>>(
      key, x, sens, keys_map, kernels, biases, sim, x16, kb16, bb16);
  gemm_poly<<<dim3(BATCH / 128, 8), 256, 0, stream>>>(x16, kb16, bb16, sim, part);
  reduce_parts<<<(BATCH * UDIM) / (256 * 4), 256, 0, stream>>>(part, out);
}